// Round 12
// baseline (1546.017 us; speedup 1.0000x reference)
//
#include <hip/hip_runtime.h>
#include <math.h>

#define DIM 1024
#define THREE_DIM 3072
#define INNER 4096
#define NTOK 4096
#define NPAIR 8192
#define NEXP 8
#define MAXMB 72   // sum ceil(cnt_e/128) <= 8192/128 + 8
#define PARTROWS (MAXMB*128)

typedef __attribute__((ext_vector_type(8))) short bf16x8;
typedef __attribute__((ext_vector_type(4))) float f32x4;
typedef long fp8x8;

__device__ __forceinline__ unsigned short f2bf(float f){
    unsigned int x = __float_as_uint(f);
    unsigned int r = x + 0x7fffu + ((x >> 16) & 1u);   // RNE
    return (unsigned short)(r >> 16);
}

__device__ __forceinline__ float bf2f(unsigned short u){
    return __uint_as_float(((unsigned int)u) << 16);
}

__device__ __forceinline__ unsigned short us4c(ushort4 v, int i){
    return i == 0 ? v.x : (i == 1 ? v.y : (i == 2 ? v.z : v.w));
}

// pack 4 fp32 -> 4 fp8 e4m3 (OCP on gfx950) in one u32
__device__ __forceinline__ unsigned int f4fp8(float a, float b, float c, float d){
    int p = __builtin_amdgcn_cvt_pk_fp8_f32(a, b, 0, false);
    p = __builtin_amdgcn_cvt_pk_fp8_f32(c, d, p, true);
    return (unsigned int)p;
}

__device__ __forceinline__ unsigned char f2fp8(float f){
    int p = __builtin_amdgcn_cvt_pk_fp8_f32(f, f, 0, false);
    return (unsigned char)(p & 0xff);
}

__device__ __forceinline__ void glds16(const void* g, void* l){
    __builtin_amdgcn_global_load_lds(
        (const __attribute__((address_space(1))) void*)g,
        (__attribute__((address_space(3))) void*)l, 16, 0, 0);
}

// chunked XCD swizzle: HW assigns block i -> XCD i%8; give XCD j the
// contiguous fid range [j*cpx, (j+1)*cpx). Requires gridDim.x % 8 == 0.
__device__ __forceinline__ int xcd_swz(){
    int cpx = gridDim.x >> 3;
    return (blockIdx.x & 7) * cpx + (blockIdx.x >> 3);
}

// ---------------- LayerNorm (fp32 in; fp32 / bf16 / fp8 out) ---------------
__global__ __launch_bounds__(256)
void ln_kernel(const float* __restrict__ X, const float* __restrict__ g,
               const float* __restrict__ b, float* __restrict__ outF,
               unsigned short* __restrict__ outB,
               unsigned char* __restrict__ outF8)
{
    int row = blockIdx.x;
    int t = threadIdx.x;
    const float4 v = *((const float4*)(X + (size_t)row*DIM) + t);
    float s = v.x + v.y + v.z + v.w;
    #pragma unroll
    for (int m = 1; m < 64; m <<= 1) s += __shfl_xor(s, m, 64);
    __shared__ float red[8];
    int wid = t >> 6, lane = t & 63;
    if (lane == 0) red[wid] = s;
    __syncthreads();
    float mu = (red[0]+red[1]+red[2]+red[3]) * (1.0f/DIM);
    float dx = v.x-mu, dy = v.y-mu, dz = v.z-mu, dw = v.w-mu;
    float s2 = dx*dx + dy*dy + dz*dz + dw*dw;
    #pragma unroll
    for (int m = 1; m < 64; m <<= 1) s2 += __shfl_xor(s2, m, 64);
    if (lane == 0) red[4+wid] = s2;
    __syncthreads();
    float var = (red[4]+red[5]+red[6]+red[7]) * (1.0f/DIM);
    float inv = rsqrtf(var + 1e-5f);
    const float4 gg = *((const float4*)g + t);
    const float4 bb = *((const float4*)b + t);
    float y0 = dx*inv*gg.x + bb.x;
    float y1 = dy*inv*gg.y + bb.y;
    float y2 = dz*inv*gg.z + bb.z;
    float y3 = dw*inv*gg.w + bb.w;
    if (outF){
        float4 o; o.x=y0; o.y=y1; o.z=y2; o.w=y3;
        *((float4*)(outF + (size_t)row*DIM) + t) = o;
    }
    if (outB){
        ushort4 u; u.x=f2bf(y0); u.y=f2bf(y1); u.z=f2bf(y2); u.w=f2bf(y3);
        *((ushort4*)(outB + (size_t)row*DIM) + t) = u;
    }
    if (outF8){
        *((unsigned int*)(outF8 + (size_t)row*DIM) + t) = f4fp8(y0, y1, y2, y3);
    }
}

// ---------------- bf16 MFMA GEMM (BK=64, single buffer) --------------------
// 1D grid (XCD-swizzled), fid = my*gnx + nx (nx fastest -> A-panel L2 reuse).
// MODE 0: bf16 store.  MODE 1: fp32 store of acc + bias[col] + resid[row,col]
template<int MODE>
__global__ __launch_bounds__(256)
void gemm_bf(const unsigned short* __restrict__ A,
             const unsigned short* __restrict__ BT,
             int K, int N, int gnx,
             const float* __restrict__ bias, const float* __restrict__ resid,
             unsigned short* __restrict__ outB, float* __restrict__ outF)
{
    __shared__ __align__(16) unsigned short As[128*64];
    __shared__ __align__(16) unsigned short Bs[128*64];
    int fid = xcd_swz();
    int nx = fid % gnx, my = fid / gnx;
    int m0 = my * 128, n0 = nx * 128;
    int t = threadIdx.x, lane = t & 63, wid = t >> 6;
    size_t aoff[4], boff[4];
    #pragma unroll
    for (int it = 0; it < 4; ++it){
        int chunk = it*256 + wid*64 + lane;
        int r = chunk >> 3, c16 = chunk & 7;
        int c16s = c16 ^ (r & 7);
        aoff[it] = (size_t)(m0 + r)*K + (size_t)(c16s*8);
        boff[it] = (size_t)(n0 + r)*K + (size_t)(c16s*8);
    }
    int wm = wid >> 1, wn = wid & 1;
    f32x4 acc[4][4];
    #pragma unroll
    for (int mi = 0; mi < 4; ++mi)
        #pragma unroll
        for (int ni = 0; ni < 4; ++ni)
            #pragma unroll
            for (int q = 0; q < 4; ++q) acc[mi][ni][q] = 0.f;

    for (int k0 = 0; k0 < K; k0 += 64){
        __syncthreads();
        #pragma unroll
        for (int it = 0; it < 4; ++it){
            glds16(A  + aoff[it] + k0, As + (size_t)(it*256 + wid*64)*8);
            glds16(BT + boff[it] + k0, Bs + (size_t)(it*256 + wid*64)*8);
        }
        __syncthreads();
        bf16x8 af[4][2], bg[4][2];
        #pragma unroll
        for (int mi = 0; mi < 4; ++mi){
            int row = wm*64 + mi*16 + (lane & 15);
            #pragma unroll
            for (int ks = 0; ks < 2; ++ks){
                int cg = (ks*4 + (lane >> 4)) ^ (row & 7);
                af[mi][ks] = *(const bf16x8*)&As[row*64 + cg*8];
            }
        }
        #pragma unroll
        for (int ni = 0; ni < 4; ++ni){
            int row = wn*64 + ni*16 + (lane & 15);
            #pragma unroll
            for (int ks = 0; ks < 2; ++ks){
                int cg = (ks*4 + (lane >> 4)) ^ (row & 7);
                bg[ni][ks] = *(const bf16x8*)&Bs[row*64 + cg*8];
            }
        }
        #pragma unroll
        for (int ks = 0; ks < 2; ++ks)
            #pragma unroll
            for (int mi = 0; mi < 4; ++mi)
                #pragma unroll
                for (int ni = 0; ni < 4; ++ni)
                    acc[mi][ni] = __builtin_amdgcn_mfma_f32_16x16x32_bf16(
                                      af[mi][ks], bg[ni][ks], acc[mi][ni], 0, 0, 0);
    }
    #pragma unroll
    for (int mi = 0; mi < 4; ++mi){
        #pragma unroll
        for (int ni = 0; ni < 4; ++ni){
            int ccol = n0 + wn*64 + ni*16 + (lane & 15);
            #pragma unroll
            for (int j = 0; j < 4; ++j){
                int row = m0 + wm*64 + mi*16 + (lane >> 4)*4 + j;
                float v = acc[mi][ni][j];
                if (MODE == 0){
                    outB[(size_t)row*N + ccol] = f2bf(v);
                } else {
                    outF[(size_t)row*N + ccol] =
                        v + bias[ccol] + resid[(size_t)row*N + ccol];
                }
            }
        }
    }
}

// ---------------- attention v4: bf16 MFMA flash, 64x64 tiles ---------------
__global__ __launch_bounds__(256)
void attn4_kernel(const unsigned short* __restrict__ qkv,
                  unsigned short* __restrict__ O,
                  const float* __restrict__ threshp)
{
    __shared__ __align__(16) unsigned short Qs[64*64];
    __shared__ __align__(16) unsigned short Ks[64*64];
    __shared__ __align__(16) unsigned short Vp[8*520];   // [jc][d][jj] pad 520
    __shared__ __align__(16) unsigned short Ps[4*1024];  // per-wave P [16][64]

    int fid = xcd_swz();
    int qt = fid & 15, hh = (fid >> 4) & 15, bb = fid >> 8;
    int t = threadIdx.x, lane = t & 63, w = t >> 6;
    int arow = lane & 15, agrp = lane >> 4;
    int qrow0 = bb*1024 + qt*64;
    float thresh = threshp[0];

    #pragma unroll
    for (int it = 0; it < 2; ++it){
        int chunk = it*256 + w*64 + lane;
        int r = chunk >> 3, c16 = chunk & 7;
        glds16(qkv + (size_t)(qrow0+r)*3072 + hh*64 + ((c16 ^ (r & 7))*8),
               Qs + (size_t)(it*256 + w*64)*8);
    }
    __syncthreads();
    bf16x8 qf[2];
    {
        int row = w*16 + arow;
        #pragma unroll
        for (int s = 0; s < 2; ++s){
            int c = (s*4 + agrp) ^ (row & 7);
            qf[s] = *(const bf16x8*)&Qs[row*64 + c*8];
        }
    }

    float m_[4], l_[4];
    f32x4 acc[4];
    #pragma unroll
    for (int j = 0; j < 4; ++j){ m_[j] = -INFINITY; l_[j] = 0.f; }
    #pragma unroll
    for (int d4 = 0; d4 < 4; ++d4)
        #pragma unroll
        for (int j = 0; j < 4; ++j) acc[d4][j] = 0.f;

    for (int kt = 0; kt < 16; ++kt){
        __syncthreads();
        int krow0 = bb*1024 + kt*64;
        #pragma unroll
        for (int it = 0; it < 2; ++it){
            int chunk = it*256 + w*64 + lane;
            int r = chunk >> 3, c16 = chunk & 7;
            glds16(qkv + (size_t)(krow0+r)*3072 + 1024 + hh*64 + ((c16 ^ (r & 7))*8),
                   Ks + (size_t)(it*256 + w*64)*8);
        }
        if (t < 128){
            int jc = t & 7, d0 = (t >> 3) * 4;
            ushort4 u[8];
            #pragma unroll
            for (int jj = 0; jj < 8; ++jj)
                u[jj] = *(const ushort4*)(qkv + (size_t)(krow0 + jc*8 + jj)*3072
                                          + 2048 + hh*64 + d0);
            #pragma unroll
            for (int i = 0; i < 4; ++i){
                ushort4 a, b;
                a.x = us4c(u[0], i); a.y = us4c(u[1], i);
                a.z = us4c(u[2], i); a.w = us4c(u[3], i);
                b.x = us4c(u[4], i); b.y = us4c(u[5], i);
                b.z = us4c(u[6], i); b.w = us4c(u[7], i);
                *(ushort4*)&Vp[jc*520 + (d0+i)*8]     = a;
                *(ushort4*)&Vp[jc*520 + (d0+i)*8 + 4] = b;
            }
        }
        __syncthreads();

        f32x4 sv[4];
        #pragma unroll
        for (int n = 0; n < 4; ++n)
            #pragma unroll
            for (int j = 0; j < 4; ++j) sv[n][j] = 0.f;
        #pragma unroll
        for (int n = 0; n < 4; ++n){
            int krow = n*16 + arow;
            #pragma unroll
            for (int s = 0; s < 2; ++s){
                int c = (s*4 + agrp) ^ (krow & 7);
                bf16x8 kf = *(const bf16x8*)&Ks[krow*64 + c*8];
                sv[n] = __builtin_amdgcn_mfma_f32_16x16x32_bf16(qf[s], kf, sv[n], 0, 0, 0);
            }
        }
        #pragma unroll
        for (int n = 0; n < 4; ++n)
            #pragma unroll
            for (int j = 0; j < 4; ++j){
                float s = sv[n][j] * 0.125f;
                sv[n][j] = (s < thresh) ? -1e9f : s;
            }
        float tmax[4], fac[4], rsum[4];
        #pragma unroll
        for (int j = 0; j < 4; ++j)
            tmax[j] = fmaxf(fmaxf(sv[0][j], sv[1][j]), fmaxf(sv[2][j], sv[3][j]));
        #pragma unroll
        for (int msk = 1; msk < 16; msk <<= 1)
            #pragma unroll
            for (int j = 0; j < 4; ++j)
                tmax[j] = fmaxf(tmax[j], __shfl_xor(tmax[j], msk, 64));
        #pragma unroll
        for (int j = 0; j < 4; ++j){
            float mn = fmaxf(m_[j], tmax[j]);
            fac[j] = __expf(m_[j] - mn);
            m_[j] = mn;
        }
        #pragma unroll
        for (int n = 0; n < 4; ++n)
            #pragma unroll
            for (int j = 0; j < 4; ++j)
                sv[n][j] = __expf(sv[n][j] - m_[j]);
        #pragma unroll
        for (int j = 0; j < 4; ++j)
            rsum[j] = sv[0][j] + sv[1][j] + sv[2][j] + sv[3][j];
        #pragma unroll
        for (int msk = 1; msk < 16; msk <<= 1)
            #pragma unroll
            for (int j = 0; j < 4; ++j)
                rsum[j] += __shfl_xor(rsum[j], msk, 64);
        #pragma unroll
        for (int j = 0; j < 4; ++j)
            l_[j] = l_[j]*fac[j] + rsum[j];
        #pragma unroll
        for (int n = 0; n < 4; ++n){
            int col = n*16 + arow;
            #pragma unroll
            for (int j = 0; j < 4; ++j){
                int r = agrp*4 + j;
                int idx = r*64 + (((col>>3) ^ (r&7)) << 3) + (col & 7);
                Ps[w*1024 + idx] = f2bf(sv[n][j]);
            }
        }
        #pragma unroll
        for (int d4 = 0; d4 < 4; ++d4)
            #pragma unroll
            for (int j = 0; j < 4; ++j) acc[d4][j] *= fac[j];
        #pragma unroll
        for (int s = 0; s < 2; ++s){
            int c = (s*4 + agrp) ^ (arow & 7);
            bf16x8 pa = *(const bf16x8*)&Ps[w*1024 + arow*64 + c*8];
            int jc = s*4 + agrp;
            #pragma unroll
            for (int d4 = 0; d4 < 4; ++d4){
                int dcol = d4*16 + arow;
                bf16x8 vb = *(const bf16x8*)&Vp[jc*520 + dcol*8];
                acc[d4] = __builtin_amdgcn_mfma_f32_16x16x32_bf16(pa, vb, acc[d4], 0, 0, 0);
            }
        }
    }
    #pragma unroll
    for (int j = 0; j < 4; ++j){
        float inv = 1.0f / l_[j];
        int row = qrow0 + w*16 + agrp*4 + j;
        #pragma unroll
        for (int d4 = 0; d4 < 4; ++d4)
            O[(size_t)row*1024 + hh*64 + d4*16 + arow] = f2bf(acc[d4][j] * inv);
    }
}

// ---------------- gate: logits, softmax probs, top-2 ----------------
__global__ __launch_bounds__(64)
void gate_kernel(const float* __restrict__ h2, const float* __restrict__ gw,
                 float* __restrict__ probs, int* __restrict__ top_i,
                 float* __restrict__ top_w)
{
    int tk = blockIdx.x;
    int lane = threadIdx.x;
    const float* hr = h2 + (size_t)tk*DIM;
    float acc[8];
    #pragma unroll
    for (int e = 0; e < 8; ++e) acc[e] = 0.f;
    for (int d = lane; d < DIM; d += 64){
        float hv = hr[d];
        const float* grow = gw + d*8;
        #pragma unroll
        for (int e = 0; e < 8; ++e) acc[e] = fmaf(hv, grow[e], acc[e]);
    }
    #pragma unroll
    for (int m = 1; m < 64; m <<= 1)
        #pragma unroll
        for (int e = 0; e < 8; ++e) acc[e] += __shfl_xor(acc[e], m, 64);
    if (lane == 0){
        float mx = acc[0];
        #pragma unroll
        for (int e = 1; e < 8; ++e) mx = fmaxf(mx, acc[e]);
        float p[8], s = 0.f;
        #pragma unroll
        for (int e = 0; e < 8; ++e){ p[e] = __expf(acc[e]-mx); s += p[e]; }
        float invs = 1.f/s;
        #pragma unroll
        for (int e = 0; e < 8; ++e) probs[(size_t)tk*8+e] = p[e]*invs;
        int i0 = 0; float v0 = acc[0];
        #pragma unroll
        for (int e = 1; e < 8; ++e) if (acc[e] > v0){ v0 = acc[e]; i0 = e; }
        int i1 = -1; float v1 = -INFINITY;
        #pragma unroll
        for (int e = 0; e < 8; ++e) if (e != i0 && acc[e] > v1){ v1 = acc[e]; i1 = e; }
        float w0 = 1.f/(1.f + __expf(v1 - v0));
        top_i[tk*2]   = i0; top_i[tk*2+1] = i1;
        top_w[tk*2]   = w0; top_w[tk*2+1] = 1.f - w0;
    }
}

// ---------------- aux loss ----------------
__global__ __launch_bounds__(256)
void aux_kernel(const float* __restrict__ probs, float* __restrict__ dout)
{
    int t = threadIdx.x;
    float acc[8];
    #pragma unroll
    for (int e = 0; e < 8; ++e) acc[e] = 0.f;
    for (int r = t; r < NTOK; r += 256){
        const float* pr = probs + (size_t)r*8;
        #pragma unroll
        for (int e = 0; e < 8; ++e) acc[e] += pr[e];
    }
    #pragma unroll
    for (int m = 1; m < 64; m <<= 1)
        #pragma unroll
        for (int e = 0; e < 8; ++e) acc[e] += __shfl_xor(acc[e], m, 64);
    __shared__ float red[4][8];
    int wid = t >> 6, lane = t & 63;
    if (lane == 0)
        for (int e = 0; e < 8; ++e) red[wid][e] = acc[e];
    __syncthreads();
    if (t == 0){
        float aux = 0.f;
        for (int e = 0; e < 8; ++e){
            float S = red[0][e]+red[1][e]+red[2][e]+red[3][e];
            aux += S*S;
        }
        dout[(size_t)NTOK*DIM] = aux * (8.0f/NTOK);
    }
}

// ---------------- routing: expert-grouped compaction + inverse map --------
__global__ __launch_bounds__(512)
void routing_kernel(const int* __restrict__ topi, int* __restrict__ perm,
                    int* __restrict__ mblk_e, int* __restrict__ tokslot)
{
    __shared__ int cnt[8];
    __shared__ int obase[8];
    int t = threadIdx.x, w = t >> 6, lane = t & 63;
    int c = 0;
    for (int i0 = 0; i0 < NPAIR; i0 += 64){
        int e = topi[i0 + lane];
        c += (e == w) ? 1 : 0;
    }
    #pragma unroll
    for (int m = 1; m < 64; m <<= 1) c += __shfl_xor(c, m, 64);
    if (lane == 0) cnt[w] = c;
    __syncthreads();
    if (t == 0){
        int mb = 0;
        for (int e = 0; e < 8; ++e){
            obase[e] = mb*128;
            int nb = (cnt[e] + 127) >> 7;
            for (int k = 0; k < nb; ++k) mblk_e[mb++] = e;
        }
        for (; mb < MAXMB; ++mb) mblk_e[mb] = -1;
    }
    __syncthreads();
    for (int i = t; i < MAXMB*128; i += 512) perm[i] = -1;
    __syncthreads();
    int base = obase[w];
    for (int i0 = 0; i0 < NPAIR; i0 += 64){
        int p = i0 + lane;
        int e = topi[p];
        bool mt = (e == w);
        unsigned long long mk = __ballot(mt);
        int rank = __popcll(mk & ((1ull << lane) - 1ull));
        if (mt){
            perm[base + rank] = p;
            tokslot[p] = base + rank;
        }
        base += __popcll(mk);
    }
}

// -------- grouped fp8 MFMA GEMM, 128x256 tile, 8 waves, BK=64 -------------
// 1D grid (XCD-swizzled): fid = (kk*GMB + mb)*GNX + nx (nx fastest).
// A/B fp8 e4m3. LDS linear, source chunk-swizzle ^(r&3) (4 chunks/row).
// MODE 2: act8[mbrow,n] = fp8(fastgelu(h2f8[tok] @ w1T8[e] + b1[e]))
// MODE 3 (KSPLIT=2): part[kk][mbrow][n] = bf16(tile + (kk==0)*b2)
template<int MODE>
__global__ __launch_bounds__(512, 8)
void gemm_moe8(const unsigned char* __restrict__ Abase,
               const unsigned char* __restrict__ BTbase,
               int K, int N, int lda,
               const int* __restrict__ perm, const int* __restrict__ mblk_e,
               const float* __restrict__ bias,
               unsigned char* __restrict__ actout,
               unsigned short* __restrict__ partout)
{
    const int GNX = (MODE == 2) ? (INNER/256) : (DIM/256);
    int fid = xcd_swz();
    int nx = fid % GNX;
    int rest = fid / GNX;
    int mb = rest % MAXMB;
    int kk = rest / MAXMB;
    int e = mblk_e[mb];
    if (e < 0) return;
    int kspan = (MODE == 2) ? K : (K >> 1);
    int kbeg = kk * kspan, kend = kbeg + kspan;

    __shared__ __align__(16) unsigned char As[128*64];   // 8 KB
    __shared__ __align__(16) unsigned char Bs[256*64];   // 16 KB
    __shared__ int permL[128];
    int t = threadIdx.x;
    if (MODE == 2 && t < 128) permL[t] = perm[mb*128 + t];
    __syncthreads();
    int lane = t & 63, wid = t >> 6;           // wid 0..7
    int wm = wid >> 2, wn = wid & 3;           // 2 x 4 wave grid
    int n0 = nx * 256;
    const unsigned char* BT = BTbase + (size_t)e * (size_t)N * (size_t)K;
    // A: 512 chunks (128 rows x 4), B: 1024 chunks (256 rows x 4)
    size_t aoff;
    {
        int chunk = t;
        int r = chunk >> 2, c16 = chunk & 3;
        int c16s = c16 ^ (r & 3);
        size_t ar;
        if (MODE == 2){ int p = permL[r]; ar = (p >= 0) ? (size_t)(p >> 1) : 0; }
        else          { ar = (size_t)(mb*128 + r); }
        aoff = ar*(size_t)lda + (size_t)(c16s*16);
    }
    size_t boff[2];
    #pragma unroll
    for (int it = 0; it < 2; ++it){
        int chunk = it*512 + t;
        int r = chunk >> 2, c16 = chunk & 3;
        int c16s = c16 ^ (r & 3);
        boff[it] = (size_t)(n0 + r)*(size_t)K + (size_t)(c16s*16);
    }
    f32x4 acc[4][4];
    #pragma unroll
    for (int mi = 0; mi < 4; ++mi)
        #pragma unroll
        for (int ni = 0; ni < 4; ++ni)
            #pragma unroll
            for (int q = 0; q < 4; ++q) acc[mi][ni][q] = 0.f;

    for (int k0 = kbeg; k0 < kend; k0 += 64){
        __syncthreads();
        glds16(Abase + aoff + k0, As + (size_t)(wid*64 + lane)*16);
        #pragma unroll
        for (int it = 0; it < 2; ++it)
            glds16(BT + boff[it] + k0, Bs + (size_t)(it*512 + wid*64 + lane)*16);
        __syncthreads();   // compiler drains vmcnt before s_barrier
        #pragma unroll
        for (int ks = 0; ks < 2; ++ks){
            fp8x8 af[4], bg[4];
            #pragma unroll
            for (int mi = 0; mi < 4; ++mi){
                int row = wm*64 + mi*16 + (lane & 15);
                int o = ks*4 + (lane >> 4);
                int lc = (o >> 1) ^ (row & 3);
                af[mi] = *(const fp8x8*)&As[row*64 + lc*16 + (o & 1)*8];
            }
            #pragma unroll
            for (int ni = 0; ni < 4; ++ni){
                int row = wn*64 + ni*16 + (lane & 15);
                int o = ks*4 + (lane >> 4);
                int lc = (o >> 1) ^ (row & 3);
                bg[ni] = *(const fp8x8*)&Bs[row*64 + lc*16 + (o & 1)*8];
            }
            #pragma unroll
            for (int mi = 0; mi < 4; ++mi)
                #pragma unroll
                for (int ni = 0; ni < 4; ++ni)
                    acc[mi][ni] = __builtin_amdgcn_mfma_f32_16x16x32_fp8_fp8(
                                      af[mi], bg[ni], acc[mi][ni], 0, 0, 0);
        }
    }
    #pragma unroll
    for (int mi = 0; mi < 4; ++mi){
        #pragma unroll
        for (int ni = 0; ni < 4; ++ni){
            int ccol = n0 + wn*64 + ni*16 + (lane & 15);
            float bv = (kk == 0) ? bias[(size_t)e*N + ccol] : 0.f;
            #pragma unroll
            for (int j = 0; j < 4; ++j){
                int rloc = wm*64 + mi*16 + (lane >> 4)*4 + j;
                float v = acc[mi][ni][j];
                if (MODE == 2){
                    float gx = v + bv;
                    // fast tanh-GELU: gx * sigmoid(gx*(1.5957691+0.0713548*gx^2))
                    float z2 = gx * fmaf(gx*gx, 0.07135481283f, 1.595769122f);
                    float ex = __expf(-z2);
                    float gl = gx * __builtin_amdgcn_rcpf(1.0f + ex);
                    actout[(size_t)(mb*128 + rloc)*N + ccol] = f2fp8(gl);
                } else {
                    partout[((size_t)kk*PARTROWS + mb*128 + rloc)*N + ccol] = f2bf(v + bv);
                }
            }
        }
    }
}

// ---- combine: out[t] += w0*(part0[s0]+part1[s0]) + w1*(part0[s1]+part1[s1])
__global__ __launch_bounds__(256)
void combine_kernel(const unsigned short* __restrict__ part,
                    const int* __restrict__ tokslot,
                    const float* __restrict__ topw,
                    float* __restrict__ out)
{
    int tk = blockIdx.x, t = threadIdx.x;
    int s0 = tokslot[tk*2], s1 = tokslot[tk*2+1];
    float w0 = topw[tk*2], w1 = topw[tk*2+1];
    ushort4 a0 = *((const ushort4*)(part + (size_t)s0*DIM) + t);
    ushort4 a1 = *((const ushort4*)(part + ((size_t)PARTROWS + s0)*DIM) + t);
    ushort4 b0 = *((const ushort4*)(part + (size_t)s1*DIM) + t);
    ushort4 b1 = *((const ushort4*)(part + ((size_t)PARTROWS + s1)*DIM) + t);
    float4* o4 = (float4*)(out + (size_t)tk*DIM) + t;
    float4 o = *o4;
    o.x += w0*(bf2f(a0.x) + bf2f(a1.x)) + w1*(bf2f(b0.x) + bf2f(b1.x));
    o.y += w0*(bf2f(a0.y) + bf2f(a1.y)) + w1*(bf2f(b0.y) + bf2f(b1.y));
    o.z += w0*(bf2f(a0.z) + bf2f(a1.z)) + w1*(bf2f(b0.z) + bf2f(b1.z));
    o.w += w0*(bf2f(a0.w) + bf2f(a1.w)) + w1*(bf2f(b0.w) + bf2f(b1.w));
    *o4 = o;
}

// ---------------- transpose + cast fp32 -> bf16: WT[n][k] = W[k][n] --------
__global__ __launch_bounds__(256)
void transp_cast(const float* __restrict__ W, unsigned short* __restrict__ WT,
                 int K, int N)
{
    __shared__ float tile[32][33];
    size_t base = (size_t)blockIdx.z * (size_t)K * (size_t)N;
    const float* Wp = W + base;
    unsigned short* Tp = WT + base;
    int t = threadIdx.x;
    int r = t >> 3, c4 = (t & 7) << 2;
    int n0 = blockIdx.x << 5, k0 = blockIdx.y << 5;
    float4 v = *(const float4*)(Wp + (size_t)(k0+r)*N + n0 + c4);
    tile[r][c4+0] = v.x; tile[r][c4+1] = v.y;
    tile[r][c4+2] = v.z; tile[r][c4+3] = v.w;
    __syncthreads();
    ushort4 u;
    u.x = f2bf(tile[c4+0][r]);
    u.y = f2bf(tile[c4+1][r]);
    u.z = f2bf(tile[c4+2][r]);
    u.w = f2bf(tile[c4+3][r]);
    *(ushort4*)(Tp + (size_t)(n0+r)*K + k0 + c4) = u;
}

// ---------------- transpose + cast fp32 -> fp8: WT[n][k] = W[k][n] ---------
__global__ __launch_bounds__(256)
void transp_cast8(const float* __restrict__ W, unsigned char* __restrict__ WT,
                  int K, int N)
{
    __shared__ float tile[32][33];
    size_t base = (size_t)blockIdx.z * (size_t)K * (size_t)N;
    const float* Wp = W + base;
    unsigned char* Tp = WT + base;
    int t = threadIdx.x;
    int r = t >> 3, c4 = (t & 7) << 2;
    int n0 = blockIdx.x << 5, k0 = blockIdx.y << 5;
    float4 v = *(const float4*)(Wp + (size_t)(k0+r)*N + n0 + c4);
    tile[r][c4+0] = v.x; tile[r][c4+1] = v.y;
    tile[r][c4+2] = v.z; tile[r][c4+3] = v.w;
    __syncthreads();
    unsigned int u = f4fp8(tile[c4+0][r], tile[c4+1][r], tile[c4+2][r], tile[c4+3][r]);
    *(unsigned int*)(Tp + (size_t)(n0+r)*K + k0 + c4) = u;
}

// ---------------- launch ----------------
extern "C" void kernel_launch(void* const* d_in, const int* in_sizes, int n_in,
                              void* d_out, int out_size, void* d_ws, size_t ws_size,
                              hipStream_t stream)
{
    const float* x      = (const float*)d_in[0];
    const float* qkv_w  = (const float*)d_in[1];
    const float* out_w  = (const float*)d_in[2];
    const float* out_b  = (const float*)d_in[3];
    const float* thresh = (const float*)d_in[4];
    const float* ln1_g  = (const float*)d_in[5];
    const float* ln1_b  = (const float*)d_in[6];
    const float* ln2_g  = (const float*)d_in[7];
    const float* ln2_b  = (const float*)d_in[8];
    const float* gate_w = (const float*)d_in[9];
    const float* w1     = (const float*)d_in[10];
    const float* b1     = (const float*)d_in[11];
    const float* w2     = (const float*)d_in[12];
    const float* b2     = (const float*)d_in[13];
    float* out = (float*)d_out;
    char* ws = (char*)d_ws;

    const size_t MB = (size_t)1 << 20;
    unsigned short* h1bf  = (unsigned short*)(ws);            // 8 MB
    unsigned short* qkvbf = (unsigned short*)(ws + 8*MB);     // 24 MB
    unsigned short* obf   = (unsigned short*)(ws + 32*MB);    // 8 MB
    float*          h2    = (float*)(ws + 40*MB);             // 16 MB
    unsigned char*  h2f8  = (unsigned char*)(ws + 56*MB);     // 4 MB
    unsigned short* qwT   = (unsigned short*)(ws + 64*MB);    // 6 MB
    unsigned short* owT   = (unsigned short*)(ws + 70*MB);    // 2 MB
    unsigned char*  w1T8  = (unsigned char*)(ws + 72*MB);     // 32 MB
    unsigned char*  w2T8  = (unsigned char*)(ws + 104*MB);    // 32 MB
    unsigned char*  act8  = (unsigned char*)(ws + 136*MB);    // 37.8 MB
    float* probs          = (float*)(ws + 276*MB);            // 128 KB
    int*   top_i          = (int*)(ws + 276*MB + 131072);     // 32 KB
    float* top_w          = (float*)(ws + 276*MB + 163840);   // 32 KB
    int*   perm           = (int*)(ws + 276*MB + 196608);     // 40 KB
    int*   mblk           = (int*)(ws + 276*MB + 237568);     // small
    int*   tokslot        = (int*)(ws + 276*MB + 241664);     // 32 KB
    unsigned short* part  = (unsigned short*)(ws + 280*MB);   // 37.8 MB (2 planes)

    transp_cast<<<dim3(THREE_DIM/32, DIM/32, 1), 256, 0, stream>>>(qkv_w, qwT, DIM, THREE_DIM);
    transp_cast<<<dim3(DIM/32, DIM/32, 1), 256, 0, stream>>>(out_w, owT, DIM, DIM);

    ln_kernel<<<NTOK, 256, 0, stream>>>(x, ln1_g, ln1_b, nullptr, h1bf, nullptr);
    gemm_bf<0><<<(THREE_DIM/128)*(NTOK/128), 256, 0, stream>>>(
        h1bf, qwT, DIM, THREE_DIM, THREE_DIM/128, nullptr, nullptr, qkvbf, nullptr);
    attn4_kernel<<<16*16*4, 256, 0, stream>>>(qkvbf, obf, thresh);
    gemm_bf<1><<<(DIM/128)*(NTOK/128), 256, 0, stream>>>(
        obf, owT, DIM, DIM, DIM/128, out_b, x, nullptr, out);
    ln_kernel<<<NTOK, 256, 0, stream>>>(out, ln2_g, ln2_b, h2, nullptr, h2f8);
    gate_kernel<<<NTOK, 64, 0, stream>>>(h2, gate_w, probs, top_i, top_w);
    aux_kernel<<<1, 256, 0, stream>>>(probs, out);
    routing_kernel<<<1, 512, 0, stream>>>(top_i, perm, mblk, tokslot);

    // MoE expert weights -> fp8
    transp_cast8<<<dim3(INNER/32, DIM/32, NEXP), 256, 0, stream>>>(w1, w1T8, DIM, INNER);
    transp_cast8<<<dim3(DIM/32, INNER/32, NEXP), 256, 0, stream>>>(w2, w2T8, INNER, DIM);

    gemm_moe8<2><<<(INNER/256)*MAXMB, 512, 0, stream>>>(
        h2f8, w1T8, DIM, INNER, DIM, perm, mblk, b1, act8, nullptr);
    gemm_moe8<3><<<(DIM/256)*MAXMB*2, 512, 0, stream>>>(
        act8, w2T8, INNER, DIM, INNER, perm, mblk, b2, nullptr, part);
    combine_kernel<<<NTOK, 256, 0, stream>>>(part, tokslot, top_w, out);
}

// Round 13
// 486.652 us; speedup vs baseline: 3.1768x; 3.1768x over previous
//
#include <hip/hip_runtime.h>
#include <math.h>

#define DIM 1024
#define THREE_DIM 3072
#define INNER 4096
#define NTOK 4096
#define NPAIR 8192
#define NEXP 8
#define MAXMB 72   // sum ceil(cnt_e/128) <= 8192/128 + 8
#define PARTROWS (MAXMB*128)

typedef __attribute__((ext_vector_type(8))) short bf16x8;
typedef __attribute__((ext_vector_type(4))) float f32x4;
typedef long fp8x8;

__device__ __forceinline__ unsigned short f2bf(float f){
    unsigned int x = __float_as_uint(f);
    unsigned int r = x + 0x7fffu + ((x >> 16) & 1u);   // RNE
    return (unsigned short)(r >> 16);
}

__device__ __forceinline__ float bf2f(unsigned short u){
    return __uint_as_float(((unsigned int)u) << 16);
}

__device__ __forceinline__ unsigned short us4c(ushort4 v, int i){
    return i == 0 ? v.x : (i == 1 ? v.y : (i == 2 ? v.z : v.w));
}

// pack 4 fp32 -> 4 fp8 e4m3 (OCP on gfx950) in one u32
__device__ __forceinline__ unsigned int f4fp8(float a, float b, float c, float d){
    int p = __builtin_amdgcn_cvt_pk_fp8_f32(a, b, 0, false);
    p = __builtin_amdgcn_cvt_pk_fp8_f32(c, d, p, true);
    return (unsigned int)p;
}

__device__ __forceinline__ unsigned char f2fp8(float f){
    int p = __builtin_amdgcn_cvt_pk_fp8_f32(f, f, 0, false);
    return (unsigned char)(p & 0xff);
}

__device__ __forceinline__ void glds16(const void* g, void* l){
    __builtin_amdgcn_global_load_lds(
        (const __attribute__((address_space(1))) void*)g,
        (__attribute__((address_space(3))) void*)l, 16, 0, 0);
}

// chunked XCD swizzle: HW assigns block i -> XCD i%8; give XCD j the
// contiguous fid range [j*cpx, (j+1)*cpx). Requires gridDim.x % 8 == 0.
__device__ __forceinline__ int xcd_swz(){
    int cpx = gridDim.x >> 3;
    return (blockIdx.x & 7) * cpx + (blockIdx.x >> 3);
}

// ---------------- LayerNorm (fp32 in; fp32 / bf16 / fp8 out) ---------------
__global__ __launch_bounds__(256)
void ln_kernel(const float* __restrict__ X, const float* __restrict__ g,
               const float* __restrict__ b, float* __restrict__ outF,
               unsigned short* __restrict__ outB,
               unsigned char* __restrict__ outF8)
{
    int row = blockIdx.x;
    int t = threadIdx.x;
    const float4 v = *((const float4*)(X + (size_t)row*DIM) + t);
    float s = v.x + v.y + v.z + v.w;
    #pragma unroll
    for (int m = 1; m < 64; m <<= 1) s += __shfl_xor(s, m, 64);
    __shared__ float red[8];
    int wid = t >> 6, lane = t & 63;
    if (lane == 0) red[wid] = s;
    __syncthreads();
    float mu = (red[0]+red[1]+red[2]+red[3]) * (1.0f/DIM);
    float dx = v.x-mu, dy = v.y-mu, dz = v.z-mu, dw = v.w-mu;
    float s2 = dx*dx + dy*dy + dz*dz + dw*dw;
    #pragma unroll
    for (int m = 1; m < 64; m <<= 1) s2 += __shfl_xor(s2, m, 64);
    if (lane == 0) red[4+wid] = s2;
    __syncthreads();
    float var = (red[4]+red[5]+red[6]+red[7]) * (1.0f/DIM);
    float inv = rsqrtf(var + 1e-5f);
    const float4 gg = *((const float4*)g + t);
    const float4 bb = *((const float4*)b + t);
    float y0 = dx*inv*gg.x + bb.x;
    float y1 = dy*inv*gg.y + bb.y;
    float y2 = dz*inv*gg.z + bb.z;
    float y3 = dw*inv*gg.w + bb.w;
    if (outF){
        float4 o; o.x=y0; o.y=y1; o.z=y2; o.w=y3;
        *((float4*)(outF + (size_t)row*DIM) + t) = o;
    }
    if (outB){
        ushort4 u; u.x=f2bf(y0); u.y=f2bf(y1); u.z=f2bf(y2); u.w=f2bf(y3);
        *((ushort4*)(outB + (size_t)row*DIM) + t) = u;
    }
    if (outF8){
        *((unsigned int*)(outF8 + (size_t)row*DIM) + t) = f4fp8(y0, y1, y2, y3);
    }
}

// ---------------- bf16 MFMA GEMM (BK=64, single buffer) --------------------
// 1D grid (XCD-swizzled), fid = my*gnx + nx (nx fastest -> A-panel L2 reuse).
// MODE 0: bf16 store.  MODE 1: fp32 store of acc + bias[col] + resid[row,col]
template<int MODE>
__global__ __launch_bounds__(256)
void gemm_bf(const unsigned short* __restrict__ A,
             const unsigned short* __restrict__ BT,
             int K, int N, int gnx,
             const float* __restrict__ bias, const float* __restrict__ resid,
             unsigned short* __restrict__ outB, float* __restrict__ outF)
{
    __shared__ __align__(16) unsigned short As[128*64];
    __shared__ __align__(16) unsigned short Bs[128*64];
    int fid = xcd_swz();
    int nx = fid % gnx, my = fid / gnx;
    int m0 = my * 128, n0 = nx * 128;
    int t = threadIdx.x, lane = t & 63, wid = t >> 6;
    size_t aoff[4], boff[4];
    #pragma unroll
    for (int it = 0; it < 4; ++it){
        int chunk = it*256 + wid*64 + lane;
        int r = chunk >> 3, c16 = chunk & 7;
        int c16s = c16 ^ (r & 7);
        aoff[it] = (size_t)(m0 + r)*K + (size_t)(c16s*8);
        boff[it] = (size_t)(n0 + r)*K + (size_t)(c16s*8);
    }
    int wm = wid >> 1, wn = wid & 1;
    f32x4 acc[4][4];
    #pragma unroll
    for (int mi = 0; mi < 4; ++mi)
        #pragma unroll
        for (int ni = 0; ni < 4; ++ni)
            #pragma unroll
            for (int q = 0; q < 4; ++q) acc[mi][ni][q] = 0.f;

    for (int k0 = 0; k0 < K; k0 += 64){
        __syncthreads();
        #pragma unroll
        for (int it = 0; it < 4; ++it){
            glds16(A  + aoff[it] + k0, As + (size_t)(it*256 + wid*64)*8);
            glds16(BT + boff[it] + k0, Bs + (size_t)(it*256 + wid*64)*8);
        }
        __syncthreads();
        bf16x8 af[4][2], bg[4][2];
        #pragma unroll
        for (int mi = 0; mi < 4; ++mi){
            int row = wm*64 + mi*16 + (lane & 15);
            #pragma unroll
            for (int ks = 0; ks < 2; ++ks){
                int cg = (ks*4 + (lane >> 4)) ^ (row & 7);
                af[mi][ks] = *(const bf16x8*)&As[row*64 + cg*8];
            }
        }
        #pragma unroll
        for (int ni = 0; ni < 4; ++ni){
            int row = wn*64 + ni*16 + (lane & 15);
            #pragma unroll
            for (int ks = 0; ks < 2; ++ks){
                int cg = (ks*4 + (lane >> 4)) ^ (row & 7);
                bg[ni][ks] = *(const bf16x8*)&Bs[row*64 + cg*8];
            }
        }
        #pragma unroll
        for (int ks = 0; ks < 2; ++ks)
            #pragma unroll
            for (int mi = 0; mi < 4; ++mi)
                #pragma unroll
                for (int ni = 0; ni < 4; ++ni)
                    acc[mi][ni] = __builtin_amdgcn_mfma_f32_16x16x32_bf16(
                                      af[mi][ks], bg[ni][ks], acc[mi][ni], 0, 0, 0);
    }
    #pragma unroll
    for (int mi = 0; mi < 4; ++mi){
        #pragma unroll
        for (int ni = 0; ni < 4; ++ni){
            int ccol = n0 + wn*64 + ni*16 + (lane & 15);
            #pragma unroll
            for (int j = 0; j < 4; ++j){
                int row = m0 + wm*64 + mi*16 + (lane >> 4)*4 + j;
                float v = acc[mi][ni][j];
                if (MODE == 0){
                    outB[(size_t)row*N + ccol] = f2bf(v);
                } else {
                    outF[(size_t)row*N + ccol] =
                        v + bias[ccol] + resid[(size_t)row*N + ccol];
                }
            }
        }
    }
}

// ---------------- attention v4: bf16 MFMA flash, 64x64 tiles ---------------
__global__ __launch_bounds__(256)
void attn4_kernel(const unsigned short* __restrict__ qkv,
                  unsigned short* __restrict__ O,
                  const float* __restrict__ threshp)
{
    __shared__ __align__(16) unsigned short Qs[64*64];
    __shared__ __align__(16) unsigned short Ks[64*64];
    __shared__ __align__(16) unsigned short Vp[8*520];   // [jc][d][jj] pad 520
    __shared__ __align__(16) unsigned short Ps[4*1024];  // per-wave P [16][64]

    int fid = xcd_swz();
    int qt = fid & 15, hh = (fid >> 4) & 15, bb = fid >> 8;
    int t = threadIdx.x, lane = t & 63, w = t >> 6;
    int arow = lane & 15, agrp = lane >> 4;
    int qrow0 = bb*1024 + qt*64;
    float thresh = threshp[0];

    #pragma unroll
    for (int it = 0; it < 2; ++it){
        int chunk = it*256 + w*64 + lane;
        int r = chunk >> 3, c16 = chunk & 7;
        glds16(qkv + (size_t)(qrow0+r)*3072 + hh*64 + ((c16 ^ (r & 7))*8),
               Qs + (size_t)(it*256 + w*64)*8);
    }
    __syncthreads();
    bf16x8 qf[2];
    {
        int row = w*16 + arow;
        #pragma unroll
        for (int s = 0; s < 2; ++s){
            int c = (s*4 + agrp) ^ (row & 7);
            qf[s] = *(const bf16x8*)&Qs[row*64 + c*8];
        }
    }

    float m_[4], l_[4];
    f32x4 acc[4];
    #pragma unroll
    for (int j = 0; j < 4; ++j){ m_[j] = -INFINITY; l_[j] = 0.f; }
    #pragma unroll
    for (int d4 = 0; d4 < 4; ++d4)
        #pragma unroll
        for (int j = 0; j < 4; ++j) acc[d4][j] = 0.f;

    for (int kt = 0; kt < 16; ++kt){
        __syncthreads();
        int krow0 = bb*1024 + kt*64;
        #pragma unroll
        for (int it = 0; it < 2; ++it){
            int chunk = it*256 + w*64 + lane;
            int r = chunk >> 3, c16 = chunk & 7;
            glds16(qkv + (size_t)(krow0+r)*3072 + 1024 + hh*64 + ((c16 ^ (r & 7))*8),
                   Ks + (size_t)(it*256 + w*64)*8);
        }
        if (t < 128){
            int jc = t & 7, d0 = (t >> 3) * 4;
            ushort4 u[8];
            #pragma unroll
            for (int jj = 0; jj < 8; ++jj)
                u[jj] = *(const ushort4*)(qkv + (size_t)(krow0 + jc*8 + jj)*3072
                                          + 2048 + hh*64 + d0);
            #pragma unroll
            for (int i = 0; i < 4; ++i){
                ushort4 a, b;
                a.x = us4c(u[0], i); a.y = us4c(u[1], i);
                a.z = us4c(u[2], i); a.w = us4c(u[3], i);
                b.x = us4c(u[4], i); b.y = us4c(u[5], i);
                b.z = us4c(u[6], i); b.w = us4c(u[7], i);
                *(ushort4*)&Vp[jc*520 + (d0+i)*8]     = a;
                *(ushort4*)&Vp[jc*520 + (d0+i)*8 + 4] = b;
            }
        }
        __syncthreads();

        f32x4 sv[4];
        #pragma unroll
        for (int n = 0; n < 4; ++n)
            #pragma unroll
            for (int j = 0; j < 4; ++j) sv[n][j] = 0.f;
        #pragma unroll
        for (int n = 0; n < 4; ++n){
            int krow = n*16 + arow;
            #pragma unroll
            for (int s = 0; s < 2; ++s){
                int c = (s*4 + agrp) ^ (krow & 7);
                bf16x8 kf = *(const bf16x8*)&Ks[krow*64 + c*8];
                sv[n] = __builtin_amdgcn_mfma_f32_16x16x32_bf16(qf[s], kf, sv[n], 0, 0, 0);
            }
        }
        #pragma unroll
        for (int n = 0; n < 4; ++n)
            #pragma unroll
            for (int j = 0; j < 4; ++j){
                float s = sv[n][j] * 0.125f;
                sv[n][j] = (s < thresh) ? -1e9f : s;
            }
        float tmax[4], fac[4], rsum[4];
        #pragma unroll
        for (int j = 0; j < 4; ++j)
            tmax[j] = fmaxf(fmaxf(sv[0][j], sv[1][j]), fmaxf(sv[2][j], sv[3][j]));
        #pragma unroll
        for (int msk = 1; msk < 16; msk <<= 1)
            #pragma unroll
            for (int j = 0; j < 4; ++j)
                tmax[j] = fmaxf(tmax[j], __shfl_xor(tmax[j], msk, 64));
        #pragma unroll
        for (int j = 0; j < 4; ++j){
            float mn = fmaxf(m_[j], tmax[j]);
            fac[j] = __expf(m_[j] - mn);
            m_[j] = mn;
        }
        #pragma unroll
        for (int n = 0; n < 4; ++n)
            #pragma unroll
            for (int j = 0; j < 4; ++j)
                sv[n][j] = __expf(sv[n][j] - m_[j]);
        #pragma unroll
        for (int j = 0; j < 4; ++j)
            rsum[j] = sv[0][j] + sv[1][j] + sv[2][j] + sv[3][j];
        #pragma unroll
        for (int msk = 1; msk < 16; msk <<= 1)
            #pragma unroll
            for (int j = 0; j < 4; ++j)
                rsum[j] += __shfl_xor(rsum[j], msk, 64);
        #pragma unroll
        for (int j = 0; j < 4; ++j)
            l_[j] = l_[j]*fac[j] + rsum[j];
        #pragma unroll
        for (int n = 0; n < 4; ++n){
            int col = n*16 + arow;
            #pragma unroll
            for (int j = 0; j < 4; ++j){
                int r = agrp*4 + j;
                int idx = r*64 + (((col>>3) ^ (r&7)) << 3) + (col & 7);
                Ps[w*1024 + idx] = f2bf(sv[n][j]);
            }
        }
        #pragma unroll
        for (int d4 = 0; d4 < 4; ++d4)
            #pragma unroll
            for (int j = 0; j < 4; ++j) acc[d4][j] *= fac[j];
        #pragma unroll
        for (int s = 0; s < 2; ++s){
            int c = (s*4 + agrp) ^ (arow & 7);
            bf16x8 pa = *(const bf16x8*)&Ps[w*1024 + arow*64 + c*8];
            int jc = s*4 + agrp;
            #pragma unroll
            for (int d4 = 0; d4 < 4; ++d4){
                int dcol = d4*16 + arow;
                bf16x8 vb = *(const bf16x8*)&Vp[jc*520 + dcol*8];
                acc[d4] = __builtin_amdgcn_mfma_f32_16x16x32_bf16(pa, vb, acc[d4], 0, 0, 0);
            }
        }
    }
    #pragma unroll
    for (int j = 0; j < 4; ++j){
        float inv = 1.0f / l_[j];
        int row = qrow0 + w*16 + agrp*4 + j;
        #pragma unroll
        for (int d4 = 0; d4 < 4; ++d4)
            O[(size_t)row*1024 + hh*64 + d4*16 + arow] = f2bf(acc[d4][j] * inv);
    }
}

// ---------------- gate: logits, softmax probs, top-2 ----------------
__global__ __launch_bounds__(64)
void gate_kernel(const float* __restrict__ h2, const float* __restrict__ gw,
                 float* __restrict__ probs, int* __restrict__ top_i,
                 float* __restrict__ top_w)
{
    int tk = blockIdx.x;
    int lane = threadIdx.x;
    const float* hr = h2 + (size_t)tk*DIM;
    float acc[8];
    #pragma unroll
    for (int e = 0; e < 8; ++e) acc[e] = 0.f;
    for (int d = lane; d < DIM; d += 64){
        float hv = hr[d];
        const float* grow = gw + d*8;
        #pragma unroll
        for (int e = 0; e < 8; ++e) acc[e] = fmaf(hv, grow[e], acc[e]);
    }
    #pragma unroll
    for (int m = 1; m < 64; m <<= 1)
        #pragma unroll
        for (int e = 0; e < 8; ++e) acc[e] += __shfl_xor(acc[e], m, 64);
    if (lane == 0){
        float mx = acc[0];
        #pragma unroll
        for (int e = 1; e < 8; ++e) mx = fmaxf(mx, acc[e]);
        float p[8], s = 0.f;
        #pragma unroll
        for (int e = 0; e < 8; ++e){ p[e] = __expf(acc[e]-mx); s += p[e]; }
        float invs = 1.f/s;
        #pragma unroll
        for (int e = 0; e < 8; ++e) probs[(size_t)tk*8+e] = p[e]*invs;
        int i0 = 0; float v0 = acc[0];
        #pragma unroll
        for (int e = 1; e < 8; ++e) if (acc[e] > v0){ v0 = acc[e]; i0 = e; }
        int i1 = -1; float v1 = -INFINITY;
        #pragma unroll
        for (int e = 0; e < 8; ++e) if (e != i0 && acc[e] > v1){ v1 = acc[e]; i1 = e; }
        float w0 = 1.f/(1.f + __expf(v1 - v0));
        top_i[tk*2]   = i0; top_i[tk*2+1] = i1;
        top_w[tk*2]   = w0; top_w[tk*2+1] = 1.f - w0;
    }
}

// ---------------- aux loss ----------------
__global__ __launch_bounds__(256)
void aux_kernel(const float* __restrict__ probs, float* __restrict__ dout)
{
    int t = threadIdx.x;
    float acc[8];
    #pragma unroll
    for (int e = 0; e < 8; ++e) acc[e] = 0.f;
    for (int r = t; r < NTOK; r += 256){
        const float* pr = probs + (size_t)r*8;
        #pragma unroll
        for (int e = 0; e < 8; ++e) acc[e] += pr[e];
    }
    #pragma unroll
    for (int m = 1; m < 64; m <<= 1)
        #pragma unroll
        for (int e = 0; e < 8; ++e) acc[e] += __shfl_xor(acc[e], m, 64);
    __shared__ float red[4][8];
    int wid = t >> 6, lane = t & 63;
    if (lane == 0)
        for (int e = 0; e < 8; ++e) red[wid][e] = acc[e];
    __syncthreads();
    if (t == 0){
        float aux = 0.f;
        for (int e = 0; e < 8; ++e){
            float S = red[0][e]+red[1][e]+red[2][e]+red[3][e];
            aux += S*S;
        }
        dout[(size_t)NTOK*DIM] = aux * (8.0f/NTOK);
    }
}

// ---------------- routing: expert-grouped compaction + inverse map --------
__global__ __launch_bounds__(512)
void routing_kernel(const int* __restrict__ topi, int* __restrict__ perm,
                    int* __restrict__ mblk_e, int* __restrict__ tokslot)
{
    __shared__ int cnt[8];
    __shared__ int obase[8];
    int t = threadIdx.x, w = t >> 6, lane = t & 63;
    int c = 0;
    for (int i0 = 0; i0 < NPAIR; i0 += 64){
        int e = topi[i0 + lane];
        c += (e == w) ? 1 : 0;
    }
    #pragma unroll
    for (int m = 1; m < 64; m <<= 1) c += __shfl_xor(c, m, 64);
    if (lane == 0) cnt[w] = c;
    __syncthreads();
    if (t == 0){
        int mb = 0;
        for (int e = 0; e < 8; ++e){
            obase[e] = mb*128;
            int nb = (cnt[e] + 127) >> 7;
            for (int k = 0; k < nb; ++k) mblk_e[mb++] = e;
        }
        for (; mb < MAXMB; ++mb) mblk_e[mb] = -1;
    }
    __syncthreads();
    for (int i = t; i < MAXMB*128; i += 512) perm[i] = -1;
    __syncthreads();
    int base = obase[w];
    for (int i0 = 0; i0 < NPAIR; i0 += 64){
        int p = i0 + lane;
        int e = topi[p];
        bool mt = (e == w);
        unsigned long long mk = __ballot(mt);
        int rank = __popcll(mk & ((1ull << lane) - 1ull));
        if (mt){
            perm[base + rank] = p;
            tokslot[p] = base + rank;
        }
        base += __popcll(mk);
    }
}

// -------- grouped fp8 MFMA GEMM, 128x256 tile, 8 waves, BK=64 -------------
// 1D grid (XCD-swizzled): fid = (kk*GMB + mb)*GNX + nx (nx fastest).
// A/B fp8 e4m3. LDS linear, source chunk-swizzle ^(r&3) (4 chunks/row).
// MODE 2: act8[mbrow,n] = fp8(fastgelu(h2f8[tok] @ w1T8[e] + b1[e]))
// MODE 3 (KSPLIT=2): part[kk][mbrow][n] = bf16(tile + (kk==0)*b2)
template<int MODE>
__global__ __launch_bounds__(512, 4)   // R12 bug: (512,8) forced 32 VGPR -> spill
void gemm_moe8(const unsigned char* __restrict__ Abase,
               const unsigned char* __restrict__ BTbase,
               int K, int N, int lda,
               const int* __restrict__ perm, const int* __restrict__ mblk_e,
               const float* __restrict__ bias,
               unsigned char* __restrict__ actout,
               unsigned short* __restrict__ partout)
{
    const int GNX = (MODE == 2) ? (INNER/256) : (DIM/256);
    int fid = xcd_swz();
    int nx = fid % GNX;
    int rest = fid / GNX;
    int mb = rest % MAXMB;
    int kk = rest / MAXMB;
    int e = mblk_e[mb];
    if (e < 0) return;
    int kspan = (MODE == 2) ? K : (K >> 1);
    int kbeg = kk * kspan, kend = kbeg + kspan;

    __shared__ __align__(16) unsigned char As[128*64];   // 8 KB
    __shared__ __align__(16) unsigned char Bs[256*64];   // 16 KB
    __shared__ int permL[128];
    int t = threadIdx.x;
    if (MODE == 2 && t < 128) permL[t] = perm[mb*128 + t];
    __syncthreads();
    int lane = t & 63, wid = t >> 6;           // wid 0..7
    int wm = wid >> 2, wn = wid & 3;           // 2 x 4 wave grid
    int n0 = nx * 256;
    const unsigned char* BT = BTbase + (size_t)e * (size_t)N * (size_t)K;
    // A: 512 chunks (128 rows x 4), B: 1024 chunks (256 rows x 4)
    size_t aoff;
    {
        int chunk = t;
        int r = chunk >> 2, c16 = chunk & 3;
        int c16s = c16 ^ (r & 3);
        size_t ar;
        if (MODE == 2){ int p = permL[r]; ar = (p >= 0) ? (size_t)(p >> 1) : 0; }
        else          { ar = (size_t)(mb*128 + r); }
        aoff = ar*(size_t)lda + (size_t)(c16s*16);
    }
    size_t boff[2];
    #pragma unroll
    for (int it = 0; it < 2; ++it){
        int chunk = it*512 + t;
        int r = chunk >> 2, c16 = chunk & 3;
        int c16s = c16 ^ (r & 3);
        boff[it] = (size_t)(n0 + r)*(size_t)K + (size_t)(c16s*16);
    }
    f32x4 acc[4][4];
    #pragma unroll
    for (int mi = 0; mi < 4; ++mi)
        #pragma unroll
        for (int ni = 0; ni < 4; ++ni)
            #pragma unroll
            for (int q = 0; q < 4; ++q) acc[mi][ni][q] = 0.f;

    for (int k0 = kbeg; k0 < kend; k0 += 64){
        __syncthreads();
        glds16(Abase + aoff + k0, As + (size_t)(wid*64 + lane)*16);
        #pragma unroll
        for (int it = 0; it < 2; ++it)
            glds16(BT + boff[it] + k0, Bs + (size_t)(it*512 + wid*64 + lane)*16);
        __syncthreads();   // compiler drains vmcnt before s_barrier
        #pragma unroll
        for (int ks = 0; ks < 2; ++ks){
            fp8x8 af[4], bg[4];
            #pragma unroll
            for (int mi = 0; mi < 4; ++mi){
                int row = wm*64 + mi*16 + (lane & 15);
                int o = ks*4 + (lane >> 4);
                int lc = (o >> 1) ^ (row & 3);
                af[mi] = *(const fp8x8*)&As[row*64 + lc*16 + (o & 1)*8];
            }
            #pragma unroll
            for (int ni = 0; ni < 4; ++ni){
                int row = wn*64 + ni*16 + (lane & 15);
                int o = ks*4 + (lane >> 4);
                int lc = (o >> 1) ^ (row & 3);
                bg[ni] = *(const fp8x8*)&Bs[row*64 + lc*16 + (o & 1)*8];
            }
            #pragma unroll
            for (int mi = 0; mi < 4; ++mi)
                #pragma unroll
                for (int ni = 0; ni < 4; ++ni)
                    acc[mi][ni] = __builtin_amdgcn_mfma_f32_16x16x32_fp8_fp8(
                                      af[mi], bg[ni], acc[mi][ni], 0, 0, 0);
        }
    }
    #pragma unroll
    for (int mi = 0; mi < 4; ++mi){
        #pragma unroll
        for (int ni = 0; ni < 4; ++ni){
            int ccol = n0 + wn*64 + ni*16 + (lane & 15);
            float bv = (kk == 0) ? bias[(size_t)e*N + ccol] : 0.f;
            #pragma unroll
            for (int j = 0; j < 4; ++j){
                int rloc = wm*64 + mi*16 + (lane >> 4)*4 + j;
                float v = acc[mi][ni][j];
                if (MODE == 2){
                    float gx = v + bv;
                    // fast tanh-GELU: gx * sigmoid(gx*(1.5957691+0.0713548*gx^2))
                    float z2 = gx * fmaf(gx*gx, 0.07135481283f, 1.595769122f);
                    float ex = __expf(-z2);
                    float gl = gx * __builtin_amdgcn_rcpf(1.0f + ex);
                    actout[(size_t)(mb*128 + rloc)*N + ccol] = f2fp8(gl);
                } else {
                    partout[((size_t)kk*PARTROWS + mb*128 + rloc)*N + ccol] = f2bf(v + bv);
                }
            }
        }
    }
}

// ---- combine: out[t] += w0*(part0[s0]+part1[s0]) + w1*(part0[s1]+part1[s1])
__global__ __launch_bounds__(256)
void combine_kernel(const unsigned short* __restrict__ part,
                    const int* __restrict__ tokslot,
                    const float* __restrict__ topw,
                    float* __restrict__ out)
{
    int tk = blockIdx.x, t = threadIdx.x;
    int s0 = tokslot[tk*2], s1 = tokslot[tk*2+1];
    float w0 = topw[tk*2], w1 = topw[tk*2+1];
    ushort4 a0 = *((const ushort4*)(part + (size_t)s0*DIM) + t);
    ushort4 a1 = *((const ushort4*)(part + ((size_t)PARTROWS + s0)*DIM) + t);
    ushort4 b0 = *((const ushort4*)(part + (size_t)s1*DIM) + t);
    ushort4 b1 = *((const ushort4*)(part + ((size_t)PARTROWS + s1)*DIM) + t);
    float4* o4 = (float4*)(out + (size_t)tk*DIM) + t;
    float4 o = *o4;
    o.x += w0*(bf2f(a0.x) + bf2f(a1.x)) + w1*(bf2f(b0.x) + bf2f(b1.x));
    o.y += w0*(bf2f(a0.y) + bf2f(a1.y)) + w1*(bf2f(b0.y) + bf2f(b1.y));
    o.z += w0*(bf2f(a0.z) + bf2f(a1.z)) + w1*(bf2f(b0.z) + bf2f(b1.z));
    o.w += w0*(bf2f(a0.w) + bf2f(a1.w)) + w1*(bf2f(b0.w) + bf2f(b1.w));
    *o4 = o;
}

// ---------------- transpose + cast fp32 -> bf16: WT[n][k] = W[k][n] --------
__global__ __launch_bounds__(256)
void transp_cast(const float* __restrict__ W, unsigned short* __restrict__ WT,
                 int K, int N)
{
    __shared__ float tile[32][33];
    size_t base = (size_t)blockIdx.z * (size_t)K * (size_t)N;
    const float* Wp = W + base;
    unsigned short* Tp = WT + base;
    int t = threadIdx.x;
    int r = t >> 3, c4 = (t & 7) << 2;
    int n0 = blockIdx.x << 5, k0 = blockIdx.y << 5;
    float4 v = *(const float4*)(Wp + (size_t)(k0+r)*N + n0 + c4);
    tile[r][c4+0] = v.x; tile[r][c4+1] = v.y;
    tile[r][c4+2] = v.z; tile[r][c4+3] = v.w;
    __syncthreads();
    ushort4 u;
    u.x = f2bf(tile[c4+0][r]);
    u.y = f2bf(tile[c4+1][r]);
    u.z = f2bf(tile[c4+2][r]);
    u.w = f2bf(tile[c4+3][r]);
    *(ushort4*)(Tp + (size_t)(n0+r)*K + k0 + c4) = u;
}

// ---------------- transpose + cast fp32 -> fp8: WT[n][k] = W[k][n] ---------
__global__ __launch_bounds__(256)
void transp_cast8(const float* __restrict__ W, unsigned char* __restrict__ WT,
                  int K, int N)
{
    __shared__ float tile[32][33];
    size_t base = (size_t)blockIdx.z * (size_t)K * (size_t)N;
    const float* Wp = W + base;
    unsigned char* Tp = WT + base;
    int t = threadIdx.x;
    int r = t >> 3, c4 = (t & 7) << 2;
    int n0 = blockIdx.x << 5, k0 = blockIdx.y << 5;
    float4 v = *(const float4*)(Wp + (size_t)(k0+r)*N + n0 + c4);
    tile[r][c4+0] = v.x; tile[r][c4+1] = v.y;
    tile[r][c4+2] = v.z; tile[r][c4+3] = v.w;
    __syncthreads();
    unsigned int u = f4fp8(tile[c4+0][r], tile[c4+1][r], tile[c4+2][r], tile[c4+3][r]);
    *(unsigned int*)(Tp + (size_t)(n0+r)*K + k0 + c4) = u;
}

// ---------------- launch ----------------
extern "C" void kernel_launch(void* const* d_in, const int* in_sizes, int n_in,
                              void* d_out, int out_size, void* d_ws, size_t ws_size,
                              hipStream_t stream)
{
    const float* x      = (const float*)d_in[0];
    const float* qkv_w  = (const float*)d_in[1];
    const float* out_w  = (const float*)d_in[2];
    const float* out_b  = (const float*)d_in[3];
    const float* thresh = (const float*)d_in[4];
    const float* ln1_g  = (const float*)d_in[5];
    const float* ln1_b  = (const float*)d_in[6];
    const float* ln2_g  = (const float*)d_in[7];
    const float* ln2_b  = (const float*)d_in[8];
    const float* gate_w = (const float*)d_in[9];
    const float* w1     = (const float*)d_in[10];
    const float* b1     = (const float*)d_in[11];
    const float* w2     = (const float*)d_in[12];
    const float* b2     = (const float*)d_in[13];
    float* out = (float*)d_out;
    char* ws = (char*)d_ws;

    const size_t MB = (size_t)1 << 20;
    unsigned short* h1bf  = (unsigned short*)(ws);            // 8 MB
    unsigned short* qkvbf = (unsigned short*)(ws + 8*MB);     // 24 MB
    unsigned short* obf   = (unsigned short*)(ws + 32*MB);    // 8 MB
    float*          h2    = (float*)(ws + 40*MB);             // 16 MB
    unsigned char*  h2f8  = (unsigned char*)(ws + 56*MB);     // 4 MB
    unsigned short* qwT   = (unsigned short*)(ws + 64*MB);    // 6 MB
    unsigned short* owT   = (unsigned short*)(ws + 70*MB);    // 2 MB
    unsigned char*  w1T8  = (unsigned char*)(ws + 72*MB);     // 32 MB
    unsigned char*  w2T8  = (unsigned char*)(ws + 104*MB);    // 32 MB
    unsigned char*  act8  = (unsigned char*)(ws + 136*MB);    // 37.8 MB
    float* probs          = (float*)(ws + 276*MB);            // 128 KB
    int*   top_i          = (int*)(ws + 276*MB + 131072);     // 32 KB
    float* top_w          = (float*)(ws + 276*MB + 163840);   // 32 KB
    int*   perm           = (int*)(ws + 276*MB + 196608);     // 40 KB
    int*   mblk           = (int*)(ws + 276*MB + 237568);     // small
    int*   tokslot        = (int*)(ws + 276*MB + 241664);     // 32 KB
    unsigned short* part  = (unsigned short*)(ws + 280*MB);   // 37.8 MB (2 planes)

    transp_cast<<<dim3(THREE_DIM/32, DIM/32, 1), 256, 0, stream>>>(qkv_w, qwT, DIM, THREE_DIM);
    transp_cast<<<dim3(DIM/32, DIM/32, 1), 256, 0, stream>>>(out_w, owT, DIM, DIM);

    ln_kernel<<<NTOK, 256, 0, stream>>>(x, ln1_g, ln1_b, nullptr, h1bf, nullptr);
    gemm_bf<0><<<(THREE_DIM/128)*(NTOK/128), 256, 0, stream>>>(
        h1bf, qwT, DIM, THREE_DIM, THREE_DIM/128, nullptr, nullptr, qkvbf, nullptr);
    attn4_kernel<<<16*16*4, 256, 0, stream>>>(qkvbf, obf, thresh);
    gemm_bf<1><<<(DIM/128)*(NTOK/128), 256, 0, stream>>>(
        obf, owT, DIM, DIM, DIM/128, out_b, x, nullptr, out);
    ln_kernel<<<NTOK, 256, 0, stream>>>(out, ln2_g, ln2_b, h2, nullptr, h2f8);
    gate_kernel<<<NTOK, 64, 0, stream>>>(h2, gate_w, probs, top_i, top_w);
    aux_kernel<<<1, 256, 0, stream>>>(probs, out);
    routing_kernel<<<1, 512, 0, stream>>>(top_i, perm, mblk, tokslot);

    // MoE expert weights -> fp8
    transp_cast8<<<dim3(INNER/32, DIM/32, NEXP), 256, 0, stream>>>(w1, w1T8, DIM, INNER);
    transp_cast8<<<dim3(DIM/32, INNER/32, NEXP), 256, 0, stream>>>(w2, w2T8, INNER, DIM);

    gemm_moe8<2><<<(INNER/256)*MAXMB, 512, 0, stream>>>(
        h2f8, w1T8, DIM, INNER, DIM, perm, mblk, b1, act8, nullptr);
    gemm_moe8<3><<<(DIM/256)*MAXMB*2, 512, 0, stream>>>(
        act8, w2T8, INNER, DIM, INNER, perm, mblk, b2, nullptr, part);
    combine_kernel<<<NTOK, 256, 0, stream>>>(part, tokslot, top_w, out);
}